// Round 4
// baseline (289.550 us; speedup 1.0000x reference)
//
#include <hip/hip_runtime.h>
#include <hip/hip_bf16.h>
#include <stdint.h>

typedef _Float16 f16;
typedef _Float16 f16x8 __attribute__((ext_vector_type(8)));
typedef float f32x16 __attribute__((ext_vector_type(16)));
typedef float f32x4 __attribute__((ext_vector_type(4)));
typedef uint32_t u32x4 __attribute__((ext_vector_type(4)));
typedef uint32_t u32x2 __attribute__((ext_vector_type(2)));

#define MFMA(A, B, C) __builtin_amdgcn_mfma_f32_32x32x16_f16((A), (B), (C), 0, 0, 0)

// ---------------------------------------------------------------------------
// Kernel 1: x NCHW f32 [32,256,64,64] -> xt2 f16, MFMA-native layout.
// (unchanged, correctness-proven)
// ---------------------------------------------------------------------------
__global__ __launch_bounds__(256) void nchw_to_nhwc_f16(
    const float* __restrict__ x, f16* __restrict__ xt) {
  __shared__ __align__(16) uint32_t tile[64 * 128];  // 32768 B
  const int bh = blockIdx.x;  // b*64 + h
  const int t = threadIdx.x;
  const float* src = x + (size_t)(bh >> 6) * (256 * 4096) + (bh & 63) * 64;

  const int w4 = t & 15;            // float4 index along w
  const int cq = t >> 4;            // c-quad 0..15
  const int xorv = 4 * (w4 & 7);    // = 4*((w>>2)&7) since w = w4*4+jw
#pragma unroll
  for (int it = 0; it < 4; ++it) {
    const int c0 = it * 64 + cq * 4;
    float4 v0 = *(const float4*)(src + (size_t)(c0 + 0) * 4096 + w4 * 4);
    float4 v1 = *(const float4*)(src + (size_t)(c0 + 1) * 4096 + w4 * 4);
    float4 v2 = *(const float4*)(src + (size_t)(c0 + 2) * 4096 + w4 * 4);
    float4 v3 = *(const float4*)(src + (size_t)(c0 + 3) * 4096 + w4 * 4);
    const float* p0 = (const float*)&v0;
    const float* p1 = (const float*)&v1;
    const float* p2 = (const float*)&v2;
    const float* p3 = (const float*)&v3;
    const int u = it * 32 + cq * 2;  // even word index (c-pair)
#pragma unroll
    for (int jw = 0; jw < 4; ++jw) {
      f16 h0 = (f16)p0[jw], h1 = (f16)p1[jw], h2 = (f16)p2[jw], h3 = (f16)p3[jw];
      uint32_t lo = (uint32_t)__builtin_bit_cast(uint16_t, h0) |
                    ((uint32_t)__builtin_bit_cast(uint16_t, h1) << 16);
      uint32_t hi = (uint32_t)__builtin_bit_cast(uint16_t, h2) |
                    ((uint32_t)__builtin_bit_cast(uint16_t, h3) << 16);
      u32x2 pk = {lo, hi};
      const int w = w4 * 4 + jw;
      *(u32x2*)&tile[w * 128 + (u ^ xorv)] = pk;
    }
  }
  __syncthreads();
  f16* dstb = xt + (size_t)bh * 16384;
#pragma unroll
  for (int it = 0; it < 8; ++it) {
    const int n = it * 256 + t;       // local 16B-unit index, 0..2047
    const int w2 = n & 31;
    const int par = (n >> 5) & 1;
    const int g8 = n >> 6;            // c-octet 0..31
    const int w = par + 2 * w2;
    const u32x4 v = *(const u32x4*)&tile[w * 128 + ((g8 * 4) ^ (4 * ((w >> 2) & 7)))];
    *(u32x4*)(dstb + n * 8) = v;
  }
}

// ---------------------------------------------------------------------------
// Kernel 2: W [32co][256ci][9][9] f32 -> wt2 f16. (unchanged)
// ---------------------------------------------------------------------------
__global__ __launch_bounds__(256) void pack_w(const float* __restrict__ W,
                                              f16* __restrict__ wt) {
  __shared__ float lds[10368];  // [128 ci][81 kk]
  const int t = threadIdx.x;
  const int co = blockIdx.x >> 1;
  const int cih = blockIdx.x & 1;
  const float* src = W + (size_t)(co * 256 + cih * 128) * 81;
  for (int i = t; i < 10368; i += 256) lds[i] = src[i];
  __syncthreads();
  for (int j = t; j < 1296; j += 256) {
    const int kk = j >> 4;
    const int t16 = j & 15;
    const int cicl = t16 >> 2;       // cic within half, 0..3
    const int sg = t16 & 3;          // s*2 + hh
    const int cin = ((sg >> 1) & 1) * 16 + (sg & 1) * 8;  // ci offset in 32
    f16 tmp[8];
#pragma unroll
    for (int e = 0; e < 8; ++e)
      tmp[e] = (f16)lds[(cicl * 32 + cin + e) * 81 + kk];
    const int cic = cih * 4 + cicl;
    *(f16x8*)&wt[(size_t)(((kk * 8 + cic) * 4 + sg) * 32 + co) * 8] = *(f16x8*)tmp;
  }
}

// ---------------------------------------------------------------------------
// Kernel 3: direct conv — r4: B REGISTER RING + 2 pairs/wave.
// r3 post-mortem: each MFMA consumed a private 1KB LDS B-read -> CU LDS port
// (~128B/cyc) caps MfmaUtil at ~25% (measured ~20%). Fix = cut LDS bytes
// per MFMA 4x:
//  * B register ring: T1 (kh=j-2) reuses the fragments this wave read at
//    slab j-2 — held in 3 rotating register sets (18 frags x 3 = 216 VGPR).
//    Fresh LDS reads only for kh=j (T0). Legal at 1 wave/SIMD (<=512 VGPR).
//  * 2 oh-pairs per wave (4 accs): each fresh fragment feeds 2 pairs.
//  -> 18KB LDS reads per 72 MFMAs = 0.25KB/MFMA: port demand at full
//     matrix rate = ~128B/cyc = capacity. Cap moves 25% -> ~100%.
//  * Grid 256 = 1 block/CU (4 waves = 1 wave/SIMD, deep ILP). M-space (14
//    oh-pairs, padded 16) covered in 2 sequential in-kernel phases of 8
//    pairs so the A-row footprint stays 8 x 4KB = 32KB = L1 (r2 proved
//    blowing this sends A to L2 and caps everything).
//  * Per-slab barrier cadence + 2-slot LDS stage ring (36KB), r3-proven.
// ---------------------------------------------------------------------------
__global__ __launch_bounds__(256, 1) void conv_direct(
    const f16* __restrict__ xt, const f16* __restrict__ wt,
    float* __restrict__ convp) {
  __shared__ __align__(16) char stg[2 * 18432];  // 36864 B stage ring
  const int tid = threadIdx.x;
  const int lane = tid & 63;
  const int wave = tid >> 6;
  const int m = lane & 31;
  const int hh = lane >> 5;

  const int blk = blockIdx.x;          // 256 total = 1 per CU
  const int xcd = blk & 7;
  const int i4 = (blk >> 3) & 3;
  const int cic = blk >> 5;            // 0..7 (this block's 32-ci chunk)
  const int bimg = xcd * 4 + i4;       // image on one XCD (L2 affinity)

  const char* xb = (const char*)xt;
  const char* wb = (const char*)wt;
  const size_t cic2048 = (size_t)cic * 2048;
  const int fragoff = hh * 512 + m * 16;  // in-chunk LDS read offset

#define GLDS(G, L)                                                            \
  __builtin_amdgcn_global_load_lds(                                           \
      (const __attribute__((address_space(1))) void*)(G),                     \
      (__attribute__((address_space(3))) void*)(L), 16, 0, 0)

#define ALOAD(AB, KW, P) \
  (*(const f16x8*)((AB) + (P) * 2048 + ((KW) & 1) * 512 + ((KW) >> 1) * 16))

  // Stage slab JN's 9 kk-chunks (18432B) into slot JN&1. Lane-linear dest.
#define STAGE(JN)                                                             \
  {                                                                           \
    const int kkb = (JN) * 9;                                                 \
    char* db = stg + ((JN) & 1) * 18432;                                      \
    _Pragma("unroll") for (int i = 0; i < 4; ++i) {                           \
      const int u = tid + 256 * i;                                            \
      GLDS(wb + (size_t)(kkb + (u >> 7)) * 16384 + cic2048 + (u & 127) * 16,  \
           db + u * 16);                                                      \
    }                                                                         \
    if (tid < 128) {                                                          \
      GLDS(wb + (size_t)(kkb + 8) * 16384 + cic2048 + tid * 16,               \
           db + 16384 + tid * 16);                                            \
    }                                                                         \
  }

  for (int phase = 0; phase < 2; ++phase) {
    const int pp0 = phase * 8 + wave;      // pair 0..11 (always active)
    const int pp1 = pp0 + 4;               // pair 4..15
    const bool act0 = pp0 < 14;
    const bool act1 = pp1 < 14;
    const int pp1c = act1 ? pp1 : pp0;     // clamp: harmless dup loads
    // A lane base for pair p, slab j=0: (bimg*64 + 4p)*32768 + cic*4096
    //                                   + hh*1024 + m*16 ; +32768/slab.
    const char* ab0 = xb + ((size_t)(bimg * 64 + 4 * pp0) * 32768 +
                            cic * 4096 + hh * 1024 + m * 16);
    const char* ab1 = xb + ((size_t)(bimg * 64 + 4 * pp1c) * 32768 +
                            cic * 4096 + hh * 1024 + m * 16);

    f32x16 acc00, acc01, acc10, acc11;  // [pair][tile]
#pragma unroll
    for (int i = 0; i < 16; ++i) {
      acc00[i] = 0.f; acc01[i] = 0.f; acc10[i] = 0.f; acc11[i] = 0.f;
    }

    f16x8 bs[3][18];  // B register ring: set j%3 = slab j's 18 fragments

    STAGE(0)  // prologue (slot-0 reads of prior phase drained 2 barriers ago)

#pragma unroll
    for (int j = 0; j < 11; ++j) {
      __syncthreads();             // stage[j&1] ready
      if (j < 8) STAGE(j + 1)      // fill other slot under this slab
      if (j <= 8) {                // fresh B: kh=j -> bs[j%3]
        const char* sb = stg + (j & 1) * 18432 + fragoff;
#pragma unroll
        for (int kw = 0; kw < 9; ++kw) {
          bs[j % 3][2 * kw] = *(const f16x8*)(sb + kw * 2048);
          bs[j % 3][2 * kw + 1] = *(const f16x8*)(sb + kw * 2048 + 1024);
        }
      }
      const char* aj0 = ab0 + (size_t)j * 32768;
      const char* aj1 = ab1 + (size_t)j * 32768;
#pragma unroll
      for (int kw = 0; kw < 9; ++kw) {
        const f16x8 a00 = ALOAD(aj0, kw, 0), a01 = ALOAD(aj0, kw, 1);
        const f16x8 a10 = ALOAD(aj1, kw, 0), a11 = ALOAD(aj1, kw, 1);
        if (j <= 8) {  // T0 tiles: kh=j, fresh set
          acc00 = MFMA(a00, bs[j % 3][2 * kw], acc00);
          acc00 = MFMA(a01, bs[j % 3][2 * kw + 1], acc00);
          acc10 = MFMA(a10, bs[j % 3][2 * kw], acc10);
          acc10 = MFMA(a11, bs[j % 3][2 * kw + 1], acc10);
        }
        if (j >= 2) {  // T1 tiles: kh=j-2, set read 2 slabs ago
          acc01 = MFMA(a00, bs[(j + 1) % 3][2 * kw], acc01);
          acc01 = MFMA(a01, bs[(j + 1) % 3][2 * kw + 1], acc01);
          acc11 = MFMA(a10, bs[(j + 1) % 3][2 * kw], acc11);
          acc11 = MFMA(a11, bs[(j + 1) % 3][2 * kw + 1], acc11);
        }
      }
    }

    // Direct store: acc reg r, lane (m,hh) holds D[ow=(r&3)+8*(r>>2)+4*hh][co=m].
#define STORE_PAIR(PP, ACT, A0, A1)                                           \
    if (ACT) {                                                                \
      _Pragma("unroll") for (int tile = 0; tile < 2; ++tile) {                \
        const int oh = 2 * (PP) + tile;                                       \
        float* cp = convp + (size_t)cic * 802816 +                            \
                    ((size_t)bimg * 784 + oh * 28) * 32 + m;                  \
        const f32x16& a = tile ? (A1) : (A0);                                 \
        _Pragma("unroll") for (int rI = 0; rI < 16; ++rI) {                   \
          const int ow = (rI & 3) + 8 * (rI >> 2) + 4 * hh;                   \
          if (ow < 28) cp[ow * 32] = a[rI];                                   \
        }                                                                     \
      }                                                                       \
    }
    STORE_PAIR(pp0, act0, acc00, acc01)
    STORE_PAIR(pp1, act1, acc10, acc11)
#undef STORE_PAIR
  }
#undef STAGE
#undef ALOAD
#undef GLDS
}

// ---------------------------------------------------------------------------
// Kernel 4: epilogue. v = sum(8 partials)+bias; sq=8v^2;
// scale = sq/((1+sq)*sqrt(sq+1e-8)); y=v*scale broadcast to 8 t-slots.
// (unchanged)
// ---------------------------------------------------------------------------
__global__ __launch_bounds__(256) void epilogue(const float* __restrict__ convp,
                                                const float* __restrict__ bias,
                                                float* __restrict__ out) {
  const int gi = blockIdx.x * 256 + threadIdx.x;  // 100352 total, exact grid
  const int base = gi * 8;
  const int p = gi >> 2;
  const int co0 = (gi & 3) * 8;
  const int bi = p / 784;
  const int pix = p - bi * 784;
  f32x4 v0 = {0.f, 0.f, 0.f, 0.f}, v1 = {0.f, 0.f, 0.f, 0.f};
#pragma unroll
  for (int qq = 0; qq < 8; ++qq) {
    v0 += *(const f32x4*)&convp[(size_t)qq * 802816 + base];
    v1 += *(const f32x4*)&convp[(size_t)qq * 802816 + base + 4];
  }
  float vb[8];
#pragma unroll
  for (int jj = 0; jj < 4; ++jj) {
    vb[jj] = v0[jj] + bias[co0 + jj];
    vb[4 + jj] = v1[jj] + bias[co0 + 4 + jj];
  }
  float* ob = out + (size_t)bi * 200704 + pix * 8;
#pragma unroll
  for (int jj = 0; jj < 8; ++jj) {
    const float vv = vb[jj];
    const float sq = 8.f * vv * vv;
    const float scale = sq / ((1.f + sq) * sqrtf(sq + 1e-8f));
    const float y = vv * scale;
    const f32x4 qv = {y, y, y, y};
    float* o = ob + (size_t)(co0 + jj) * 6272;
    *(f32x4*)o = qv;
    *(f32x4*)(o + 4) = qv;
  }
}

// ---------------------------------------------------------------------------
extern "C" void kernel_launch(void* const* d_in, const int* in_sizes, int n_in,
                              void* d_out, int out_size, void* d_ws,
                              size_t ws_size, hipStream_t stream) {
  const float* x = (const float*)d_in[0];     // [32,256,64,64]
  const float* W = (const float*)d_in[1];     // [32,256,9,9]
  const float* bias = (const float*)d_in[2];  // [32]
  float* out = (float*)d_out;                 // 6422528 f32

  char* ws = (char*)d_ws;
  f16* xt = (f16*)ws;                                // 67,108,864 B
  f16* wt = (f16*)(ws + 67108864);                   //  1,327,104 B
  float* convp = (float*)(ws + 67108864 + 1327104);  // 25,690,112 B (8 parts)

  nchw_to_nhwc_f16<<<dim3(2048), dim3(256), 0, stream>>>(x, xt);
  pack_w<<<dim3(64), dim3(256), 0, stream>>>(W, wt);
  conv_direct<<<dim3(256), dim3(256), 0, stream>>>(xt, wt, convp);
  epilogue<<<dim3(392), dim3(256), 0, stream>>>(convp, bias, out);
}

// Round 5
// 274.937 us; speedup vs baseline: 1.0531x; 1.0531x over previous
//
#include <hip/hip_runtime.h>
#include <hip/hip_bf16.h>
#include <stdint.h>

typedef _Float16 f16;
typedef _Float16 f16x8 __attribute__((ext_vector_type(8)));
typedef float f32x16 __attribute__((ext_vector_type(16)));
typedef float f32x4 __attribute__((ext_vector_type(4)));
typedef uint32_t u32x4 __attribute__((ext_vector_type(4)));
typedef uint32_t u32x2 __attribute__((ext_vector_type(2)));

#define MFMA(A, B, C) __builtin_amdgcn_mfma_f32_32x32x16_f16((A), (B), (C), 0, 0, 0)

// ---------------------------------------------------------------------------
// Kernel 1: x NCHW f32 [32,256,64,64] -> xt2 f16, MFMA-native layout.
// (unchanged, correctness-proven)
// ---------------------------------------------------------------------------
__global__ __launch_bounds__(256) void nchw_to_nhwc_f16(
    const float* __restrict__ x, f16* __restrict__ xt) {
  __shared__ __align__(16) uint32_t tile[64 * 128];  // 32768 B
  const int bh = blockIdx.x;  // b*64 + h
  const int t = threadIdx.x;
  const float* src = x + (size_t)(bh >> 6) * (256 * 4096) + (bh & 63) * 64;

  const int w4 = t & 15;            // float4 index along w
  const int cq = t >> 4;            // c-quad 0..15
  const int xorv = 4 * (w4 & 7);    // = 4*((w>>2)&7) since w = w4*4+jw
#pragma unroll
  for (int it = 0; it < 4; ++it) {
    const int c0 = it * 64 + cq * 4;
    float4 v0 = *(const float4*)(src + (size_t)(c0 + 0) * 4096 + w4 * 4);
    float4 v1 = *(const float4*)(src + (size_t)(c0 + 1) * 4096 + w4 * 4);
    float4 v2 = *(const float4*)(src + (size_t)(c0 + 2) * 4096 + w4 * 4);
    float4 v3 = *(const float4*)(src + (size_t)(c0 + 3) * 4096 + w4 * 4);
    const float* p0 = (const float*)&v0;
    const float* p1 = (const float*)&v1;
    const float* p2 = (const float*)&v2;
    const float* p3 = (const float*)&v3;
    const int u = it * 32 + cq * 2;  // even word index (c-pair)
#pragma unroll
    for (int jw = 0; jw < 4; ++jw) {
      f16 h0 = (f16)p0[jw], h1 = (f16)p1[jw], h2 = (f16)p2[jw], h3 = (f16)p3[jw];
      uint32_t lo = (uint32_t)__builtin_bit_cast(uint16_t, h0) |
                    ((uint32_t)__builtin_bit_cast(uint16_t, h1) << 16);
      uint32_t hi = (uint32_t)__builtin_bit_cast(uint16_t, h2) |
                    ((uint32_t)__builtin_bit_cast(uint16_t, h3) << 16);
      u32x2 pk = {lo, hi};
      const int w = w4 * 4 + jw;
      *(u32x2*)&tile[w * 128 + (u ^ xorv)] = pk;
    }
  }
  __syncthreads();
  f16* dstb = xt + (size_t)bh * 16384;
#pragma unroll
  for (int it = 0; it < 8; ++it) {
    const int n = it * 256 + t;       // local 16B-unit index, 0..2047
    const int w2 = n & 31;
    const int par = (n >> 5) & 1;
    const int g8 = n >> 6;            // c-octet 0..31
    const int w = par + 2 * w2;
    const u32x4 v = *(const u32x4*)&tile[w * 128 + ((g8 * 4) ^ (4 * ((w >> 2) & 7)))];
    *(u32x4*)(dstb + n * 8) = v;
  }
}

// ---------------------------------------------------------------------------
// Kernel 2: W [32co][256ci][9][9] f32 -> wt2 f16. (unchanged)
// ---------------------------------------------------------------------------
__global__ __launch_bounds__(256) void pack_w(const float* __restrict__ W,
                                              f16* __restrict__ wt) {
  __shared__ float lds[10368];  // [128 ci][81 kk]
  const int t = threadIdx.x;
  const int co = blockIdx.x >> 1;
  const int cih = blockIdx.x & 1;
  const float* src = W + (size_t)(co * 256 + cih * 128) * 81;
  for (int i = t; i < 10368; i += 256) lds[i] = src[i];
  __syncthreads();
  for (int j = t; j < 1296; j += 256) {
    const int kk = j >> 4;
    const int t16 = j & 15;
    const int cicl = t16 >> 2;       // cic within half, 0..3
    const int sg = t16 & 3;          // s*2 + hh
    const int cin = ((sg >> 1) & 1) * 16 + (sg & 1) * 8;  // ci offset in 32
    f16 tmp[8];
#pragma unroll
    for (int e = 0; e < 8; ++e)
      tmp[e] = (f16)lds[(cicl * 32 + cin + e) * 81 + kk];
    const int cic = cih * 4 + cicl;
    *(f16x8*)&wt[(size_t)(((kk * 8 + cic) * 4 + sg) * 32 + co) * 8] = *(f16x8*)tmp;
  }
}

// ---------------------------------------------------------------------------
// Kernel 3: direct conv — r5: r3 dataflow + 4 waves/SIMD TLP + A prefetch.
// r3/r4 post-mortem (with corrected MFMA cost: 32x32x16 = ~8 cyc per CU,
// i.e. 32 cyc per SIMD — 4x slower than previously modeled): neither the
// LDS port nor VMEM was saturated (delivered ~28 B/cyc vs ~128 capacity).
// Both rounds were LATENCY-bound: A-loads issued just-in-time (r3 VGPR=68)
// with only 2 waves/SIMD to hide ~100-200cy L1/L2 latency. Fix the hiding
// resources, keep the proven dataflow:
//  * 512-thread blocks, 8 oh-pairs/block, grid 512 = 2 blocks/CU
//    -> 16 waves/CU = 4 waves/SIMD (2x r3). LDS 2x73.7KB = 147KB <= 160 OK.
//  * __launch_bounds__(512,4): VGPR <= 128 (est ~90) so 2 blocks/CU hold.
//  * Depth-2 A rolling prefetch (baseline-proven idiom): kw+1's A loads
//    issue while kw's MFMAs run.
//  * B staged per-slab into 4-slot LDS ring (18KB/slab, global_load_lds
//    w=16), ONE barrier per slab, T0 reads stage[j], T1 stage[j-2]. Same
//    as r3. Direct stores, 8 convp partials.
// ---------------------------------------------------------------------------
__global__ __launch_bounds__(512, 4) void conv_direct(
    const f16* __restrict__ xt, const f16* __restrict__ wt,
    float* __restrict__ convp) {
  __shared__ __align__(16) char stg[4 * 18432];  // 73728 B ring
  const int tid = threadIdx.x;
  const int lane = tid & 63;
  const int wave = tid >> 6;           // 0..7
  const int m = lane & 31;
  const int hh = lane >> 5;

  const int blk = blockIdx.x;          // 512 total = 2 per CU
  const int xcd = blk & 7;
  const int r = blk >> 3;              // 0..63
  const int i4 = r >> 4;               // 0..3
  const int rr = r & 15;
  const int og = rr >> 3;              // 0..1
  const int cic = rr & 7;              // 0..7 (this block's 32-ci chunk)
  const int bimg = xcd * 4 + i4;       // image on one XCD (L2 affinity)
  const int ohp = og * 8 + wave;       // 0..15; this wave's oh-pair
  const bool active = (ohp < 14);      // oh 28..31 is padding

  const char* xb = (const char*)xt;
  const char* wb = (const char*)wt;

  // A lane base for slab j=0: byte = (bimg*64 + 4*ohp)*32768 + cic*4096
  //                                  + hh*1024 + m*16 ; per slab += 32768.
  const char* ab = xb + ((size_t)(bimg * 64 + 4 * ohp) * 32768 +
                         cic * 4096 + hh * 1024 + m * 16);
  const size_t cic2048 = (size_t)cic * 2048;
  const int fragoff = hh * 512 + m * 16;  // in-chunk LDS read offset

#define GLDS(G, L)                                                            \
  __builtin_amdgcn_global_load_lds(                                           \
      (const __attribute__((address_space(1))) void*)(G),                     \
      (__attribute__((address_space(3))) void*)(L), 16, 0, 0)

#define ALOAD(AB, KW, P) \
  (*(const f16x8*)((AB) + (P) * 2048 + ((KW) & 1) * 512 + ((KW) >> 1) * 16))
#define LDSF(P) (*(const f16x8*)(P))

  // Stage slab JN's 9 kk-chunks (18432B = 1152 x 16B units) into ring slot
  // JN&3, spread over 512 threads. Lane-linear dest (HW requirement).
#define STAGE(JN)                                                             \
  {                                                                           \
    const int kkb = (JN) * 9;                                                 \
    char* db = stg + ((JN) & 3) * 18432;                                      \
    _Pragma("unroll") for (int i = 0; i < 2; ++i) {                           \
      const int u = tid + 512 * i;                                            \
      GLDS(wb + (size_t)(kkb + (u >> 7)) * 16384 + cic2048 + (u & 127) * 16,  \
           db + u * 16);                                                      \
    }                                                                         \
    if (tid < 128) {                                                          \
      GLDS(wb + (size_t)(kkb + 8) * 16384 + cic2048 + tid * 16,               \
           db + 18432 - 2048 + tid * 16);                                     \
    }                                                                         \
  }

  f32x16 acc0, acc1;
#pragma unroll
  for (int i = 0; i < 16; ++i) { acc0[i] = 0.f; acc1[i] = 0.f; }

  STAGE(0)  // prologue: stage slab 0 (latency paid once)

  for (int j = 0; j < 11; ++j) {
    __syncthreads();            // stage[j] ready; prior slab's LDS reads done
    if (j < 8) STAGE(j + 1)     // fill next slot under this slab's compute
    if (active) {
      const char* s0 = stg + (j & 3) * 18432 + fragoff;        // T0: kh=j
      const char* s1 = stg + ((j + 2) & 3) * 18432 + fragoff;  // T1: kh=j-2
      f16x8 a0 = ALOAD(ab, 0, 0), a1 = ALOAD(ab, 0, 1);
      if (j >= 2 && j <= 8) {
#pragma unroll
        for (int kw = 0; kw < 9; ++kw) {
          f16x8 na0, na1;
          if (kw < 8) { na0 = ALOAD(ab, kw + 1, 0); na1 = ALOAD(ab, kw + 1, 1); }
          acc0 = MFMA(a0, LDSF(s0 + kw * 2048), acc0);
          acc0 = MFMA(a1, LDSF(s0 + kw * 2048 + 1024), acc0);
          acc1 = MFMA(a0, LDSF(s1 + kw * 2048), acc1);
          acc1 = MFMA(a1, LDSF(s1 + kw * 2048 + 1024), acc1);
          a0 = na0; a1 = na1;
        }
      } else if (j < 2) {  // T0 only
#pragma unroll
        for (int kw = 0; kw < 9; ++kw) {
          f16x8 na0, na1;
          if (kw < 8) { na0 = ALOAD(ab, kw + 1, 0); na1 = ALOAD(ab, kw + 1, 1); }
          acc0 = MFMA(a0, LDSF(s0 + kw * 2048), acc0);
          acc0 = MFMA(a1, LDSF(s0 + kw * 2048 + 1024), acc0);
          a0 = na0; a1 = na1;
        }
      } else {             // j > 8: T1 only
#pragma unroll
        for (int kw = 0; kw < 9; ++kw) {
          f16x8 na0, na1;
          if (kw < 8) { na0 = ALOAD(ab, kw + 1, 0); na1 = ALOAD(ab, kw + 1, 1); }
          acc1 = MFMA(a0, LDSF(s1 + kw * 2048), acc1);
          acc1 = MFMA(a1, LDSF(s1 + kw * 2048 + 1024), acc1);
          a0 = na0; a1 = na1;
        }
      }
    }
    ab += 32768;
  }
#undef STAGE
#undef ALOAD
#undef LDSF
#undef GLDS

  // Direct store (no cross-wave reduction): acc reg r, lane (m,hh) holds
  // D[ow = (r&3)+8*(r>>2)+4*hh][co = m]. Half-wave 128B segments, coalesced.
  if (active) {
#pragma unroll
    for (int tile = 0; tile < 2; ++tile) {
      const int oh = 2 * ohp + tile;
      float* cp = convp + (size_t)cic * 802816 +
                  ((size_t)bimg * 784 + oh * 28) * 32 + m;
      const f32x16& a = tile ? acc1 : acc0;
#pragma unroll
      for (int rI = 0; rI < 16; ++rI) {
        const int ow = (rI & 3) + 8 * (rI >> 2) + 4 * hh;
        if (ow < 28) cp[ow * 32] = a[rI];
      }
    }
  }
}

// ---------------------------------------------------------------------------
// Kernel 4: epilogue. v = sum(8 partials)+bias; sq=8v^2;
// scale = sq/((1+sq)*sqrt(sq+1e-8)); y=v*scale broadcast to 8 t-slots.
// (unchanged)
// ---------------------------------------------------------------------------
__global__ __launch_bounds__(256) void epilogue(const float* __restrict__ convp,
                                                const float* __restrict__ bias,
                                                float* __restrict__ out) {
  const int gi = blockIdx.x * 256 + threadIdx.x;  // 100352 total, exact grid
  const int base = gi * 8;
  const int p = gi >> 2;
  const int co0 = (gi & 3) * 8;
  const int bi = p / 784;
  const int pix = p - bi * 784;
  f32x4 v0 = {0.f, 0.f, 0.f, 0.f}, v1 = {0.f, 0.f, 0.f, 0.f};
#pragma unroll
  for (int qq = 0; qq < 8; ++qq) {
    v0 += *(const f32x4*)&convp[(size_t)qq * 802816 + base];
    v1 += *(const f32x4*)&convp[(size_t)qq * 802816 + base + 4];
  }
  float vb[8];
#pragma unroll
  for (int jj = 0; jj < 4; ++jj) {
    vb[jj] = v0[jj] + bias[co0 + jj];
    vb[4 + jj] = v1[jj] + bias[co0 + 4 + jj];
  }
  float* ob = out + (size_t)bi * 200704 + pix * 8;
#pragma unroll
  for (int jj = 0; jj < 8; ++jj) {
    const float vv = vb[jj];
    const float sq = 8.f * vv * vv;
    const float scale = sq / ((1.f + sq) * sqrtf(sq + 1e-8f));
    const float y = vv * scale;
    const f32x4 qv = {y, y, y, y};
    float* o = ob + (size_t)(co0 + jj) * 6272;
    *(f32x4*)o = qv;
    *(f32x4*)(o + 4) = qv;
  }
}

// ---------------------------------------------------------------------------
extern "C" void kernel_launch(void* const* d_in, const int* in_sizes, int n_in,
                              void* d_out, int out_size, void* d_ws,
                              size_t ws_size, hipStream_t stream) {
  const float* x = (const float*)d_in[0];     // [32,256,64,64]
  const float* W = (const float*)d_in[1];     // [32,256,9,9]
  const float* bias = (const float*)d_in[2];  // [32]
  float* out = (float*)d_out;                 // 6422528 f32

  char* ws = (char*)d_ws;
  f16* xt = (f16*)ws;                                // 67,108,864 B
  f16* wt = (f16*)(ws + 67108864);                   //  1,327,104 B
  float* convp = (float*)(ws + 67108864 + 1327104);  // 25,690,112 B (8 parts)

  nchw_to_nhwc_f16<<<dim3(2048), dim3(256), 0, stream>>>(x, xt);
  pack_w<<<dim3(64), dim3(256), 0, stream>>>(W, wt);
  conv_direct<<<dim3(512), dim3(512), 0, stream>>>(xt, wt, convp);
  epilogue<<<dim3(392), dim3(256), 0, stream>>>(convp, bias, out);
}